// Round 4
// baseline (413.667 us; speedup 1.0000x reference)
//
#include <hip/hip_runtime.h>

// Problem dims (fixed by reference)
#define BATCH  4096
#define IN_DIM 256
#define HID    512
#define NCOL   8192            // HID * STATES

// Tiling: 128x64 block tile, 4 waves stacked on M (32 rows each), B-only LDS
#define BM 128
#define BN 64
#define BK 64

typedef __attribute__((ext_vector_type(8))) short bf16x8;
typedef __attribute__((ext_vector_type(4))) float f32x4;

// pack bf16(f0) into low16, bf16(f1) into high16 (truncation) — 1 v_perm_b32
__device__ __forceinline__ uint pack_hi(float f0, float f1) {
    return __builtin_amdgcn_perm(__builtin_bit_cast(uint, f1),
                                 __builtin_bit_cast(uint, f0), 0x07060302u);
}
__device__ __forceinline__ float hi_part(float f) {
    return __builtin_bit_cast(float, __builtin_bit_cast(uint, f) & 0xFFFF0000u);
}
// XOR swizzle within a 128B [n][k] row: byte ^= slot(n)<<4
__device__ __forceinline__ int swz(int row, int byteoff) {
    return byteoff ^ ((((row & 7) ^ ((row >> 3) & 7))) << 4);
}
__device__ __forceinline__ float tanh_fast(float x) {
    float e = __builtin_amdgcn_exp2f(x * 2.8853900817779268f); // 2*log2(e)
    float r = __builtin_amdgcn_rcpf(e + 1.0f);
    return __builtin_fmaf(-2.0f, r, 1.0f);
}

__global__ __launch_bounds__(256, 8) void mqc_mfma3_kernel(
    const float* __restrict__ x,        // [BATCH, IN_DIM]
    const float* __restrict__ hq,       // [BATCH, NCOL]
    const float* __restrict__ W,        // [IN_DIM, NCOL]
    float* __restrict__ out_mean,       // [BATCH, HID]
    float* __restrict__ out_new)        // [BATCH, NCOL]
{
    // W planes only: [64 n][64 k] bf16, hi + lo. 16 KiB total.
    __shared__ char sB[2 * BN * BK * 2];
    char* const sB_hi = sB;
    char* const sB_lo = sB + BN * BK * 2;

    const int t     = threadIdx.x;
    const int lane  = t & 63;
    const int w     = t >> 6;           // wave 0..3 -> rows w*32..w*32+31
    const int lquad = lane >> 4;        // 0..3
    const int l16   = lane & 15;
    const int row0  = blockIdx.x * BM;
    const int col0  = blockIdx.y * BN;

    // W staging coords: one 4(k)x4(n) f32 block per thread
    const int k0 = (t >> 4) * 4;        // 0..60
    const int n0 = (t & 15) * 4;        // 0..60

    f32x4 acc[2][4] = {};               // [mi][ni]; D[n][b]: row=n, col=b

    for (int kt = 0; kt < IN_DIM / BK; ++kt) {
        // ---- x: direct from global (small & cache-hot), 8 float4 ----
        float4 ax[2][2][2];             // [mi][ks][half]
        #pragma unroll
        for (int mi = 0; mi < 2; ++mi)
            #pragma unroll
            for (int ks = 0; ks < 2; ++ks) {
                const float* p = &x[(size_t)(row0 + w * 32 + mi * 16 + l16) * IN_DIM
                                    + kt * BK + ks * 32 + lquad * 8];
                ax[mi][ks][0] = *(const float4*)(p);
                ax[mi][ks][1] = *(const float4*)(p + 4);
            }

        // ---- W stage: 4x4 block, split hi/lo, transpose to [n][k], b64 writes ----
        float4 wrow[4];
        #pragma unroll
        for (int r = 0; r < 4; ++r)
            wrow[r] = *(const float4*)(&W[(size_t)(kt * BK + k0 + r) * NCOL + col0 + n0]);
        #pragma unroll
        for (int c = 0; c < 4; ++c) {
            const float f0 = ((const float*)&wrow[0])[c];
            const float f1 = ((const float*)&wrow[1])[c];
            const float f2 = ((const float*)&wrow[2])[c];
            const float f3 = ((const float*)&wrow[3])[c];
            uint2 hv, lv;
            hv.x = pack_hi(f0, f1);
            hv.y = pack_hi(f2, f3);
            lv.x = pack_hi(f0 - hi_part(f0), f1 - hi_part(f1));
            lv.y = pack_hi(f2 - hi_part(f2), f3 - hi_part(f3));
            const int off = swz(n0 + c, (n0 + c) * (BK * 2) + k0 * 2);
            *(uint2*)(sB_hi + off) = hv;
            *(uint2*)(sB_lo + off) = lv;
        }
        __syncthreads();

        // ---- 3-pass MFMA over 2 k-steps of 32; A-operand = W, B-operand = x ----
        #pragma unroll
        for (int ks = 0; ks < 2; ++ks) {
            // convert x regs -> hi/lo bf16 fragments
            bf16x8 aH[2], aL[2];
            #pragma unroll
            for (int mi = 0; mi < 2; ++mi) {
                const float* f = (const float*)&ax[mi][ks][0];
                uint4 h, l;
                h.x = pack_hi(f[0], f[1]); h.y = pack_hi(f[2], f[3]);
                h.z = pack_hi(f[4], f[5]); h.w = pack_hi(f[6], f[7]);
                l.x = pack_hi(f[0] - hi_part(f[0]), f[1] - hi_part(f[1]));
                l.y = pack_hi(f[2] - hi_part(f[2]), f[3] - hi_part(f[3]));
                l.z = pack_hi(f[4] - hi_part(f[4]), f[5] - hi_part(f[5]));
                l.w = pack_hi(f[6] - hi_part(f[6]), f[7] - hi_part(f[7]));
                aH[mi] = __builtin_bit_cast(bf16x8, h);
                aL[mi] = __builtin_bit_cast(bf16x8, l);
            }
            const int kb = ks * 64 + lquad * 16;   // byte offset in k
            bf16x8 bH[4], bL[4];
            #pragma unroll
            for (int ni = 0; ni < 4; ++ni) {
                const int row = ni * 16 + l16;
                bH[ni] = *(const bf16x8*)(sB_hi + swz(row, row * (BK * 2) + kb));
            }
            #pragma unroll
            for (int mi = 0; mi < 2; ++mi)
                #pragma unroll
                for (int ni = 0; ni < 4; ++ni)
                    acc[mi][ni] = __builtin_amdgcn_mfma_f32_16x16x32_bf16(bH[ni], aH[mi], acc[mi][ni], 0, 0, 0);
            #pragma unroll
            for (int mi = 0; mi < 2; ++mi)
                #pragma unroll
                for (int ni = 0; ni < 4; ++ni)
                    acc[mi][ni] = __builtin_amdgcn_mfma_f32_16x16x32_bf16(bH[ni], aL[mi], acc[mi][ni], 0, 0, 0);
            #pragma unroll
            for (int ni = 0; ni < 4; ++ni) {
                const int row = ni * 16 + l16;
                bL[ni] = *(const bf16x8*)(sB_lo + swz(row, row * (BK * 2) + kb));
            }
            #pragma unroll
            for (int mi = 0; mi < 2; ++mi)
                #pragma unroll
                for (int ni = 0; ni < 4; ++ni)
                    acc[mi][ni] = __builtin_amdgcn_mfma_f32_16x16x32_bf16(bL[ni], aH[mi], acc[mi][ni], 0, 0, 0);
        }
        __syncthreads();
    }

    // ---- fused epilogue: tanh(C + 0.9*h), float4 I/O, s-group mean ----
    // D[n][b]: n = col0 + ni*16 + 4*lquad + reg, b = row0 + w*32 + mi*16 + l16
    #pragma unroll
    for (int mi = 0; mi < 2; ++mi) {
        const int b = row0 + w * 32 + mi * 16 + l16;
        #pragma unroll
        for (int ni = 0; ni < 4; ++ni) {
            const int n = col0 + ni * 16 + lquad * 4;
            const float4 hv = *(const float4*)(&hq[(size_t)b * NCOL + n]);
            float4 ov;
            ov.x = tanh_fast(__builtin_fmaf(0.9f, hv.x, acc[mi][ni][0]));
            ov.y = tanh_fast(__builtin_fmaf(0.9f, hv.y, acc[mi][ni][1]));
            ov.z = tanh_fast(__builtin_fmaf(0.9f, hv.z, acc[mi][ni][2]));
            ov.w = tanh_fast(__builtin_fmaf(0.9f, hv.w, acc[mi][ni][3]));
            *(float4*)(&out_new[(size_t)b * NCOL + n]) = ov;
            // mean over the 16-wide s-group (rows of this fragment):
            // in-lane 4-sum, then sum across the 4 quads (lane bits 4,5)
            float s = (ov.x + ov.y) + (ov.z + ov.w);
            s += __shfl_xor(s, 16);
            s += __shfl_xor(s, 32);
            if (lquad == 0)
                out_mean[(size_t)b * HID + (col0 >> 4) + ni] = s * 0.0625f;
        }
    }
}

extern "C" void kernel_launch(void* const* d_in, const int* in_sizes, int n_in,
                              void* d_out, int out_size, void* d_ws, size_t ws_size,
                              hipStream_t stream) {
    const float* x  = (const float*)d_in[0];   // [4096, 256]
    const float* hq = (const float*)d_in[1];   // [4096, 512, 16]
    const float* W  = (const float*)d_in[2];   // [256, 512, 16]

    float* out_mean = (float*)d_out;                          // [4096, 512]
    float* out_new  = (float*)d_out + (size_t)BATCH * HID;    // [4096, 512, 16]

    dim3 grid(BATCH / BM, NCOL / BN);   // (32, 128)
    dim3 block(256);
    mqc_mfma3_kernel<<<grid, block, 0, stream>>>(x, hq, W, out_mean, out_new);
}

// Round 5
// 136.631 us; speedup vs baseline: 3.0276x; 3.0276x over previous
//
#include <hip/hip_runtime.h>

// Problem dims (fixed by reference)
#define BATCH  4096
#define IN_DIM 256
#define HID    512
#define NCOL   8192            // HID * STATES

// Tiling: 128x64 block tile, 4 waves stacked on M (32 rows each), B-only LDS
#define BM 128
#define BN 64
#define BK 64

typedef __attribute__((ext_vector_type(8))) short bf16x8;
typedef __attribute__((ext_vector_type(4))) float f32x4;

// pack bf16(f0) into low16, bf16(f1) into high16 (truncation) — 1 v_perm_b32
__device__ __forceinline__ uint pack_hi(float f0, float f1) {
    return __builtin_amdgcn_perm(__builtin_bit_cast(uint, f1),
                                 __builtin_bit_cast(uint, f0), 0x07060302u);
}
__device__ __forceinline__ float hi_part(float f) {
    return __builtin_bit_cast(float, __builtin_bit_cast(uint, f) & 0xFFFF0000u);
}
// XOR swizzle within a 128B [n][k] row: byte ^= slot(n)<<4
__device__ __forceinline__ int swz(int row, int byteoff) {
    return byteoff ^ ((((row & 7) ^ ((row >> 3) & 7))) << 4);
}
__device__ __forceinline__ float tanh_fast(float x) {
    float e = __builtin_amdgcn_exp2f(x * 2.8853900817779268f); // 2*log2(e)
    float r = __builtin_amdgcn_rcpf(e + 1.0f);
    return __builtin_fmaf(-2.0f, r, 1.0f);
}

// min-waves-per-EU = 4 (VGPR cap 128): round 4 proved 8 (cap 64) forces
// catastrophic scratch spills (+1.2 GB HBM traffic). Do not raise.
__global__ __launch_bounds__(256, 4) void mqc_mfma4_kernel(
    const float* __restrict__ x,        // [BATCH, IN_DIM]
    const float* __restrict__ hq,       // [BATCH, NCOL]
    const float* __restrict__ W,        // [IN_DIM, NCOL]
    float* __restrict__ out_mean,       // [BATCH, HID]
    float* __restrict__ out_new)        // [BATCH, NCOL]
{
    // W planes only: [64 n][64 k] bf16, hi + lo. 16 KiB total.
    __shared__ char sB[2 * BN * BK * 2];
    char* const sB_hi = sB;
    char* const sB_lo = sB + BN * BK * 2;

    const int t     = threadIdx.x;
    const int lane  = t & 63;
    const int w     = t >> 6;           // wave 0..3 -> rows w*32..w*32+31
    const int lquad = lane >> 4;        // 0..3
    const int l16   = lane & 15;
    const int row0  = blockIdx.x * BM;
    const int col0  = blockIdx.y * BN;

    // W staging coords: one 4(k)x4(n) f32 block per thread
    const int k0 = (t >> 4) * 4;        // 0..60
    const int n0 = (t & 15) * 4;        // 0..60

    f32x4 acc[2][4] = {};               // [mi][ni]; D[n][b]: row=n, col=b

    for (int kt = 0; kt < IN_DIM / BK; ++kt) {
        // ---- x: direct from global (small & cache-hot), 8 float4 ----
        float4 ax[2][2][2];             // [mi][ks][half]
        #pragma unroll
        for (int mi = 0; mi < 2; ++mi)
            #pragma unroll
            for (int ks = 0; ks < 2; ++ks) {
                const float* p = &x[(size_t)(row0 + w * 32 + mi * 16 + l16) * IN_DIM
                                    + kt * BK + ks * 32 + lquad * 8];
                ax[mi][ks][0] = *(const float4*)(p);
                ax[mi][ks][1] = *(const float4*)(p + 4);
            }

        // ---- W stage: 4x4 block, split hi/lo, transpose to [n][k], b64 writes ----
        float4 wrow[4];
        #pragma unroll
        for (int r = 0; r < 4; ++r)
            wrow[r] = *(const float4*)(&W[(size_t)(kt * BK + k0 + r) * NCOL + col0 + n0]);
        #pragma unroll
        for (int c = 0; c < 4; ++c) {
            const float f0 = ((const float*)&wrow[0])[c];
            const float f1 = ((const float*)&wrow[1])[c];
            const float f2 = ((const float*)&wrow[2])[c];
            const float f3 = ((const float*)&wrow[3])[c];
            uint2 hv, lv;
            hv.x = pack_hi(f0, f1);
            hv.y = pack_hi(f2, f3);
            lv.x = pack_hi(f0 - hi_part(f0), f1 - hi_part(f1));
            lv.y = pack_hi(f2 - hi_part(f2), f3 - hi_part(f3));
            const int off = swz(n0 + c, (n0 + c) * (BK * 2) + k0 * 2);
            *(uint2*)(sB_hi + off) = hv;
            *(uint2*)(sB_lo + off) = lv;
        }
        __syncthreads();

        // ---- 3-pass MFMA over 2 k-steps of 32; A-operand = W, B-operand = x ----
        #pragma unroll
        for (int ks = 0; ks < 2; ++ks) {
            // convert x regs -> hi/lo bf16 fragments
            bf16x8 aH[2], aL[2];
            #pragma unroll
            for (int mi = 0; mi < 2; ++mi) {
                const float* f = (const float*)&ax[mi][ks][0];
                uint4 h, l;
                h.x = pack_hi(f[0], f[1]); h.y = pack_hi(f[2], f[3]);
                h.z = pack_hi(f[4], f[5]); h.w = pack_hi(f[6], f[7]);
                l.x = pack_hi(f[0] - hi_part(f[0]), f[1] - hi_part(f[1]));
                l.y = pack_hi(f[2] - hi_part(f[2]), f[3] - hi_part(f[3]));
                l.z = pack_hi(f[4] - hi_part(f[4]), f[5] - hi_part(f[5]));
                l.w = pack_hi(f[6] - hi_part(f[6]), f[7] - hi_part(f[7]));
                aH[mi] = __builtin_bit_cast(bf16x8, h);
                aL[mi] = __builtin_bit_cast(bf16x8, l);
            }
            const int kb = ks * 64 + lquad * 16;   // byte offset in k
            bf16x8 bH[4], bL[4];
            #pragma unroll
            for (int ni = 0; ni < 4; ++ni) {
                const int row = ni * 16 + l16;
                bH[ni] = *(const bf16x8*)(sB_hi + swz(row, row * (BK * 2) + kb));
            }
            #pragma unroll
            for (int mi = 0; mi < 2; ++mi)
                #pragma unroll
                for (int ni = 0; ni < 4; ++ni)
                    acc[mi][ni] = __builtin_amdgcn_mfma_f32_16x16x32_bf16(bH[ni], aH[mi], acc[mi][ni], 0, 0, 0);
            #pragma unroll
            for (int mi = 0; mi < 2; ++mi)
                #pragma unroll
                for (int ni = 0; ni < 4; ++ni)
                    acc[mi][ni] = __builtin_amdgcn_mfma_f32_16x16x32_bf16(bH[ni], aL[mi], acc[mi][ni], 0, 0, 0);
            #pragma unroll
            for (int ni = 0; ni < 4; ++ni) {
                const int row = ni * 16 + l16;
                bL[ni] = *(const bf16x8*)(sB_lo + swz(row, row * (BK * 2) + kb));
            }
            #pragma unroll
            for (int mi = 0; mi < 2; ++mi)
                #pragma unroll
                for (int ni = 0; ni < 4; ++ni)
                    acc[mi][ni] = __builtin_amdgcn_mfma_f32_16x16x32_bf16(bL[ni], aH[mi], acc[mi][ni], 0, 0, 0);
        }
        __syncthreads();
    }

    // ---- fused epilogue: tanh(C + 0.9*h), float4 I/O, s-group mean ----
    // D[n][b]: n = col0 + ni*16 + 4*lquad + reg, b = row0 + w*32 + mi*16 + l16
    #pragma unroll
    for (int mi = 0; mi < 2; ++mi) {
        const int b = row0 + w * 32 + mi * 16 + l16;
        #pragma unroll
        for (int ni = 0; ni < 4; ++ni) {
            const int n = col0 + ni * 16 + lquad * 4;
            const float4 hv = *(const float4*)(&hq[(size_t)b * NCOL + n]);
            float4 ov;
            ov.x = tanh_fast(__builtin_fmaf(0.9f, hv.x, acc[mi][ni][0]));
            ov.y = tanh_fast(__builtin_fmaf(0.9f, hv.y, acc[mi][ni][1]));
            ov.z = tanh_fast(__builtin_fmaf(0.9f, hv.z, acc[mi][ni][2]));
            ov.w = tanh_fast(__builtin_fmaf(0.9f, hv.w, acc[mi][ni][3]));
            *(float4*)(&out_new[(size_t)b * NCOL + n]) = ov;
            // mean over the 16-wide s-group (rows of this fragment):
            // in-lane 4-sum, then sum across the 4 quads (lane bits 4,5)
            float s = (ov.x + ov.y) + (ov.z + ov.w);
            s += __shfl_xor(s, 16);
            s += __shfl_xor(s, 32);
            if (lquad == 0)
                out_mean[(size_t)b * HID + (col0 >> 4) + ni] = s * 0.0625f;
        }
    }
}

extern "C" void kernel_launch(void* const* d_in, const int* in_sizes, int n_in,
                              void* d_out, int out_size, void* d_ws, size_t ws_size,
                              hipStream_t stream) {
    const float* x  = (const float*)d_in[0];   // [4096, 256]
    const float* hq = (const float*)d_in[1];   // [4096, 512, 16]
    const float* W  = (const float*)d_in[2];   // [256, 512, 16]

    float* out_mean = (float*)d_out;                          // [4096, 512]
    float* out_new  = (float*)d_out + (size_t)BATCH * HID;    // [4096, 512, 16]

    dim3 grid(BATCH / BM, NCOL / BN);   // (32, 128)
    dim3 block(256);
    mqc_mfma4_kernel<<<grid, block, 0, stream>>>(x, hq, W, out_mean, out_new);
}